// Round 3
// baseline (140.394 us; speedup 1.0000x reference)
//
#include <hip/hip_runtime.h>
#include <math.h>

// Capsule routing, fused, register-resident formulation.
// Thread mapping: tid = j*32 + ns  (j = out-cap, ns = group). The 32 ns-lanes
// of one j are a contiguous half-wave -> sum over ns via __shfl_xor butterfly.
// t[j][ns][:] and Uacc[j][ns][:] live in the owning thread's registers.
// b[j,i] is never materialized: b = Uacc · (x[:,p],1)  (rank-9 in x).
// LDS: xs (x transposed, p-major, stride-12 rows for conflict-free b128),
//      stat2 (logsumexp over j, p-major), Ul (Uacc mirror for phase A only).

#define BSZ   512
#define C_IN  256
#define HW    36
#define NS    32
#define NOC   10
#define OD    16
#define ROUTE 3
#define NIC   (NS*HW)    // 1152
#define NT    320        // 5 waves; tid = j*32+ns
#define XSTR  12         // xs row stride (floats): 48B -> b128-aligned, all-bank coverage
#define USTR  9          // Ul row stride: 9*ns mod 32 hits all 32 banks

__global__ __launch_bounds__(NT, 4) void caps_kernel(
    const float* __restrict__ x,    // [BSZ, 256, 36]
    const float* __restrict__ Wc,   // [5120, 8]
    const float* __restrict__ bc,   // [5120]
    float* __restrict__ out)        // [BSZ, 10, 16]
{
    __shared__ float xs[NIC * XSTR];   // 55296 B, row r = p*32+ns, k in [0,8)
    __shared__ float stat2[NIC];       //  4608 B, idx p*32+ns
    __shared__ float Ul[NOC*NS*USTR];  // 11520 B, row j*32+ns
    // total 71424 B -> 2 blocks/CU

    const int tid = threadIdx.x;
    const float* xb = x + (size_t)blockIdx.x * (C_IN * HW);

    // ---- Stage x: x[c][p] -> xs[(p*32 + (c>>3))*XSTR + (c&7)] ----
    // 36 = 4*9, so every float4 lies within one channel c.
    for (int e4 = tid; e4 < (C_IN * HW) / 4; e4 += NT) {
        float4 v = ((const float4*)xb)[e4];
        int e = e4 * 4;
        int c = e / HW, p = e % HW;
        int ns = c >> 3, k = c & 7;
        xs[((p + 0) * 32 + ns) * XSTR + k] = v.x;
        xs[((p + 1) * 32 + ns) * XSTR + k] = v.y;
        xs[((p + 2) * 32 + ns) * XSTR + k] = v.z;
        xs[((p + 3) * 32 + ns) * XSTR + k] = v.w;
    }
    __syncthreads();

    const int j  = tid >> 5;    // 0..9
    const int ns = tid & 31;    // 0..31

    // Per-thread persistent W/bias addressing for (j, ns)
    const float*  wrow = Wc + ((size_t)ns * 160 + j * 16) * 8;  // 16 rows x 8 floats
    const float4* bc4  = (const float4*)(bc + ns * 160 + j * 16);

    float ua[9];   // cumulative routing coefficients for (j,ns); valid after it 0

    for (int it = 0; it < ROUTE; ++it) {
        // ---- Phase A: stat2[p*32+ns'] = logsumexp_j b[j,(ns',p)] ----
        if (it > 0) {
            const int a = ns, b = j;       // lane-fast a -> conflict-free
            #pragma unroll
            for (int m = 0; m < 4; ++m) {
                int p = b + 10 * m;
                if (p < HW) {
                    int row = p * 32 + a;
                    const float4* xr = (const float4*)&xs[row * XSTR];
                    float4 x0 = xr[0], x1 = xr[1];
                    float bv[NOC];
                    float mx = -1e30f;
                    #pragma unroll
                    for (int jj = 0; jj < NOC; ++jj) {
                        const float* up = &Ul[(jj * 32 + a) * USTR];
                        float bb = up[8]
                            + up[0]*x0.x + up[1]*x0.y + up[2]*x0.z + up[3]*x0.w
                            + up[4]*x1.x + up[5]*x1.y + up[6]*x1.z + up[7]*x1.w;
                        bv[jj] = bb;
                        mx = fmaxf(mx, bb);
                    }
                    float se = 0.f;
                    #pragma unroll
                    for (int jj = 0; jj < NOC; ++jj) se += __expf(bv[jj] - mx);
                    stat2[row] = mx + __logf(se);
                }
            }
            __syncthreads();
        }

        // ---- Phase B: t[k] = sum_p c(j,ns,p)*x[k,p]; cs in t[8] (registers) ----
        float t[9];
        #pragma unroll
        for (int kk = 0; kk < 9; ++kk) t[kk] = 0.f;
        if (it == 0) {
            for (int p = 0; p < HW; ++p) {
                const float4* xr = (const float4*)&xs[(p * 32 + ns) * XSTR];
                float4 x0 = xr[0], x1 = xr[1];
                t[0] += x0.x; t[1] += x0.y; t[2] += x0.z; t[3] += x0.w;
                t[4] += x1.x; t[5] += x1.y; t[6] += x1.z; t[7] += x1.w;
            }
            #pragma unroll
            for (int kk = 0; kk < 8; ++kk) t[kk] *= 0.1f;
            t[8] = 3.6f;
        } else {
            for (int p = 0; p < HW; ++p) {
                int row = p * 32 + ns;
                const float4* xr = (const float4*)&xs[row * XSTR];
                float4 x0 = xr[0], x1 = xr[1];
                float bb = ua[8]
                    + ua[0]*x0.x + ua[1]*x0.y + ua[2]*x0.z + ua[3]*x0.w
                    + ua[4]*x1.x + ua[5]*x1.y + ua[6]*x1.z + ua[7]*x1.w;
                float c = __expf(bb - stat2[row]);
                t[0] += c*x0.x; t[1] += c*x0.y; t[2] += c*x0.z; t[3] += c*x0.w;
                t[4] += c*x1.x; t[5] += c*x1.y; t[6] += c*x1.z; t[7] += c*x1.w;
                t[8] += c;
            }
        }

        // ---- Phase C: ps[d] = W[r,:]·t + bc[r]*cs; butterfly-sum over ns ----
        float bcv[16];
        {
            float4 b0 = bc4[0], b1 = bc4[1], b2 = bc4[2], b3 = bc4[3];
            bcv[0]=b0.x; bcv[1]=b0.y; bcv[2]=b0.z; bcv[3]=b0.w;
            bcv[4]=b1.x; bcv[5]=b1.y; bcv[6]=b1.z; bcv[7]=b1.w;
            bcv[8]=b2.x; bcv[9]=b2.y; bcv[10]=b2.z; bcv[11]=b2.w;
            bcv[12]=b3.x; bcv[13]=b3.y; bcv[14]=b3.z; bcv[15]=b3.w;
        }
        float ps[16];
        #pragma unroll
        for (int d = 0; d < OD; ++d) {
            const float4* w = (const float4*)(wrow + d * 8);
            float4 w0 = w[0], w1 = w[1];
            ps[d] = w0.x*t[0] + w0.y*t[1] + w0.z*t[2] + w0.w*t[3]
                  + w1.x*t[4] + w1.y*t[5] + w1.z*t[6] + w1.w*t[7]
                  + bcv[d]*t[8];
        }
        #pragma unroll
        for (int mk = 1; mk < 32; mk <<= 1) {
            #pragma unroll
            for (int d = 0; d < OD; ++d)
                ps[d] += __shfl_xor(ps[d], mk, 64);
        }
        // squash factor (computed redundantly in every lane)
        float ss = 0.f;
        #pragma unroll
        for (int d = 0; d < OD; ++d) ss += ps[d] * ps[d];
        float fc = sqrtf(ss) / (1.f + ss);

        if (it == ROUTE - 1) {
            if (ns == 0) {
                float4* o = (float4*)(out + (size_t)blockIdx.x * (NOC * OD) + j * OD);
                o[0] = make_float4(ps[0]*fc,  ps[1]*fc,  ps[2]*fc,  ps[3]*fc);
                o[1] = make_float4(ps[4]*fc,  ps[5]*fc,  ps[6]*fc,  ps[7]*fc);
                o[2] = make_float4(ps[8]*fc,  ps[9]*fc,  ps[10]*fc, ps[11]*fc);
                o[3] = make_float4(ps[12]*fc, ps[13]*fc, ps[14]*fc, ps[15]*fc);
            }
            break;
        }

        // ---- Phase D1: u[k] = sum_d v[d]*W[r,k]; ua += u; mirror to LDS ----
        float u[9];
        #pragma unroll
        for (int kk = 0; kk < 9; ++kk) u[kk] = 0.f;
        #pragma unroll
        for (int d = 0; d < OD; ++d) {
            float vv = ps[d] * fc;
            const float4* w = (const float4*)(wrow + d * 8);
            float4 w0 = w[0], w1 = w[1];
            u[0] += vv*w0.x; u[1] += vv*w0.y; u[2] += vv*w0.z; u[3] += vv*w0.w;
            u[4] += vv*w1.x; u[5] += vv*w1.y; u[6] += vv*w1.z; u[7] += vv*w1.w;
            u[8] += vv*bcv[d];
        }
        if (it == 0) {
            #pragma unroll
            for (int kk = 0; kk < 9; ++kk) ua[kk] = u[kk];
        } else {
            #pragma unroll
            for (int kk = 0; kk < 9; ++kk) ua[kk] += u[kk];
        }
        {
            float* up = &Ul[(j * 32 + ns) * USTR];
            #pragma unroll
            for (int kk = 0; kk < 9; ++kk) up[kk] = ua[kk];
        }
        __syncthreads();
    }
}

extern "C" void kernel_launch(void* const* d_in, const int* in_sizes, int n_in,
                              void* d_out, int out_size, void* d_ws, size_t ws_size,
                              hipStream_t stream) {
    const float* x  = (const float*)d_in[0];
    // d_in[1] = target (int32) — unused in forward
    const float* Wc = (const float*)d_in[2];
    const float* bc = (const float*)d_in[3];
    float* out = (float*)d_out;

    caps_kernel<<<dim3(BSZ), dim3(NT), 0, stream>>>(x, Wc, bc, out);
}